// Round 7
// baseline (168.170 us; speedup 1.0000x reference)
//
#include <hip/hip_runtime.h>
#include <hip/hip_bf16.h>

#define HEADS 4
#define ODIM 64
#define HD 256          // HEADS*ODIM
#define NEG_SLOPE 0.2f

typedef __attribute__((ext_vector_type(8))) short bf16x8;
typedef __attribute__((ext_vector_type(4))) float floatx4;
typedef __attribute__((ext_vector_type(2))) float floatx2;

// ============ pack x and W -> bf16 hi/lo MFMA fragments (one launch) ============
__global__ __launch_bounds__(256) void pack_xw(const float* __restrict__ x,
                                               const float* __restrict__ W,
                                               __hip_bfloat16* __restrict__ xh,
                                               __hip_bfloat16* __restrict__ xl,
                                               __hip_bfloat16* __restrict__ wh,
                                               __hip_bfloat16* __restrict__ wl,
                                               int K, int nxb) {
    const int b = blockIdx.x;
    const int Kc = K >> 5;
    if (b < nxb) {
        const int g = b * 256 + threadIdx.x;
        const int lane = g & 63, frag = g >> 6;
        const int kc = frag % Kc, mc = frag / Kc;
        const int l16 = lane & 15, q = lane >> 4;
        const float* src = x + (size_t)(mc * 16 + l16) * K + kc * 32 + q * 8;
        const float4 v0 = *(const float4*)src;
        const float4 v1 = *(const float4*)(src + 4);
        const float vv[8] = {v0.x, v0.y, v0.z, v0.w, v1.x, v1.y, v1.z, v1.w};
        union { __hip_bfloat16 b[8]; bf16x8 v; } H, L;
        #pragma unroll
        for (int p = 0; p < 8; ++p) {
            H.b[p] = __float2bfloat16(vv[p]);
            L.b[p] = __float2bfloat16(vv[p] - __bfloat162float(H.b[p]));
        }
        *(bf16x8*)&xh[(size_t)frag * 512 + lane * 8] = H.v;
        *(bf16x8*)&xl[(size_t)frag * 512 + lane * 8] = L.v;
    } else {
        const int g = (b - nxb) * 256 + threadIdx.x;
        const int lane = g & 63, frag = g >> 6;
        const int kc = frag % Kc, nc = frag / Kc;
        const int l16 = lane & 15, q = lane >> 4;
        union { __hip_bfloat16 b[8]; bf16x8 v; } H, L;
        #pragma unroll
        for (int p = 0; p < 8; ++p) {
            const float w = W[(size_t)(kc * 32 + q * 8 + p) * HD + nc * 16 + l16];
            H.b[p] = __float2bfloat16(w);
            L.b[p] = __float2bfloat16(w - __bfloat162float(H.b[p]));
        }
        *(bf16x8*)&wh[(size_t)frag * 512 + lane * 8] = H.v;
        *(bf16x8*)&wl[(size_t)frag * 512 + lane * 8] = L.v;
    }
}

// ============ fused GEMM: h = x@W (hi/lo bf16 MFMA) + exp epilogue + B-frag pack of h ============
__global__ __launch_bounds__(128) void gemm_fused(
    const __hip_bfloat16* __restrict__ xh, const __hip_bfloat16* __restrict__ xl,
    const __hip_bfloat16* __restrict__ wh, const __hip_bfloat16* __restrict__ wl,
    const float* __restrict__ att, float2* __restrict__ esrc, float2* __restrict__ edst,
    __hip_bfloat16* __restrict__ hbB, int n, int K) {

    __shared__ __hip_bfloat16 T[64][40];

    const int tid = threadIdx.x, wave = tid >> 6, lane = tid & 63;
    const int q = lane >> 4, l16 = lane & 15;
    const int m0 = blockIdx.x * 32;
    const int head = blockIdx.y;
    const int Kc = K >> 5;
    const int mc = (m0 >> 4) + wave;

    floatx4 acc[4] = {{0.f,0.f,0.f,0.f},{0.f,0.f,0.f,0.f},{0.f,0.f,0.f,0.f},{0.f,0.f,0.f,0.f}};

    const __hip_bfloat16* Axh = xh + (size_t)mc * Kc * 512 + lane * 8;
    const __hip_bfloat16* Axl = xl + (size_t)mc * Kc * 512 + lane * 8;
    const __hip_bfloat16* Bwh = wh + lane * 8;
    const __hip_bfloat16* Bwl = wl + lane * 8;
    #pragma unroll 2
    for (int kc = 0; kc < Kc; ++kc) {
        const bf16x8 ah = *(const bf16x8*)(Axh + (size_t)kc * 512);
        const bf16x8 al = *(const bf16x8*)(Axl + (size_t)kc * 512);
        bf16x8 bh[4], bl[4];
        #pragma unroll
        for (int nt = 0; nt < 4; ++nt) {
            const size_t fo = (size_t)((head * 4 + nt) * Kc + kc) * 512;
            bh[nt] = *(const bf16x8*)(Bwh + fo);
            bl[nt] = *(const bf16x8*)(Bwl + fo);
        }
        #pragma unroll
        for (int nt = 0; nt < 4; ++nt)
            acc[nt] = __builtin_amdgcn_mfma_f32_16x16x32_bf16(ah, bh[nt], acc[nt], 0, 0, 0);
        #pragma unroll
        for (int nt = 0; nt < 4; ++nt)
            acc[nt] = __builtin_amdgcn_mfma_f32_16x16x32_bf16(ah, bl[nt], acc[nt], 0, 0, 0);
        #pragma unroll
        for (int nt = 0; nt < 4; ++nt)
            acc[nt] = __builtin_amdgcn_mfma_f32_16x16x32_bf16(al, bh[nt], acc[nt], 0, 0, 0);
    }

    // ---- exp epilogue ----
    float as_v[4], ad_v[4];
    #pragma unroll
    for (int nt = 0; nt < 4; ++nt) {
        as_v[nt] = att[head * 2 * ODIM + nt * 16 + l16];
        ad_v[nt] = att[head * 2 * ODIM + ODIM + nt * 16 + l16];
    }
    #pragma unroll
    for (int r = 0; r < 4; ++r) {
        float ps = 0.f, pd = 0.f;
        #pragma unroll
        for (int nt = 0; nt < 4; ++nt) {
            ps = fmaf(acc[nt][r], as_v[nt], ps);
            pd = fmaf(acc[nt][r], ad_v[nt], pd);
        }
        #pragma unroll
        for (int m = 1; m <= 8; m <<= 1) {
            ps += __shfl_xor(ps, m, 64);
            pd += __shfl_xor(pd, m, 64);
        }
        if (l16 == 0) {
            const int i = m0 + wave * 16 + q * 4 + r;
            esrc[head * n + i] = make_float2(__expf(ps), __expf(NEG_SLOPE * ps));
            edst[head * n + i] = make_float2(__expf(pd), __expf(NEG_SLOPE * pd));
        }
    }

    // ---- write h tile transposed to LDS as bf16 ----
    #pragma unroll
    for (int nt = 0; nt < 4; ++nt) {
        union { __hip_bfloat16 b[4]; uint2 u; } pk;
        #pragma unroll
        for (int r = 0; r < 4; ++r) pk.b[r] = __float2bfloat16(acc[nt][r]);
        *(uint2*)&T[nt * 16 + l16][wave * 16 + q * 4] = pk.u;
    }
    __syncthreads();

    // ---- emit packed B-frags of h ----
    #pragma unroll
    for (int ffi = 0; ffi < 2; ++ffi) {
        const int f = wave + ffi * 2;   // nt
        const bf16x8 v = *(const bf16x8*)&T[f * 16 + l16][q * 8];
        const size_t frag = ((size_t)head * (n >> 5) + (m0 >> 5)) * 4 + f;
        *(bf16x8*)&hbB[frag * 512 + lane * 8] = v;
    }
}

// ============ aggregate v7: barrier-free, zero-LDS, direct adj reads, high occupancy ============
// block: 4 waves (wave = head), i-tile 32 (mt=2), K split 8-way -> 1024 blocks = 4 blocks/CU.
// Per 32-j step, each lane loads: adj int4 x4 (its own rows/j), dst-exps b128 x4, h B-frags b128 x4.
// No __syncthreads; no LDS; loads land directly in consume registers (no copy rotation).
__global__ __launch_bounds__(256, 4) void aggregate(
    const int* __restrict__ adj, const float2* __restrict__ esrc,
    const float2* __restrict__ edst, const __hip_bfloat16* __restrict__ hbB,
    float* __restrict__ outsp, float* __restrict__ densp, int n, int KR) {

    const int tid = threadIdx.x;
    const int wave = tid >> 6, lane = tid & 63;
    const int q = lane >> 4, l16 = lane & 15;
    const int i0 = blockIdx.x * 32;
    const int K0 = blockIdx.y * KR;

    // src-side exps for this lane's two rows (head = wave)
    floatx2 es12[2];
    #pragma unroll
    for (int mt = 0; mt < 2; ++mt) {
        const float2 e = esrc[wave * n + i0 + mt * 16 + l16];
        es12[mt][0] = e.x; es12[mt][1] = e.y;
    }

    // ones-column B-frag for MFMA-based denominator
    union { short s[8]; bf16x8 v; } bones;
    #pragma unroll
    for (int p = 0; p < 8; ++p) bones.s[p] = (l16 == 0) ? (short)0x3F80 : (short)0;

    floatx4 acc[2][4];
    floatx4 accd[2];
    #pragma unroll
    for (int mt = 0; mt < 2; ++mt) {
        accd[mt] = (floatx4){0.f, 0.f, 0.f, 0.f};
        #pragma unroll
        for (int nt = 0; nt < 4; ++nt) acc[mt][nt] = (floatx4){0.f, 0.f, 0.f, 0.f};
    }

    // per-lane base pointers (q*8 folded in: lane covers j = step*32 + q*8 + 0..7)
    const int* arow0 = adj + (size_t)(i0 + l16) * n + K0 + q * 8;
    const int* arow1 = arow0 + (size_t)16 * n;
    const float2* edp = edst + (size_t)wave * n + K0 + q * 8;
    const __hip_bfloat16* hb = hbB + ((size_t)wave * (n >> 5) + (K0 >> 5)) * 4 * 512 + lane * 8;

    const int NSTEP = KR >> 5;

    int4 aj[4];            // [r0 j0-3][r0 j4-7][r1 j0-3][r1 j4-7]
    // prefetch adj for step 0
    {
        const int4* p0 = (const int4*)arow0;
        const int4* p1 = (const int4*)arow1;
        aj[0] = p0[0]; aj[1] = p0[1]; aj[2] = p1[0]; aj[3] = p1[1];
    }

    for (int s = 0; s < NSTEP; ++s) {
        // ---- just-in-time loads for this step (L2-resident; TLP hides latency) ----
        float4 ced[4]; bf16x8 cbf[4];
        {
            const float4* ep = (const float4*)(edp + (size_t)s * 32);
            ced[0] = ep[0]; ced[1] = ep[1]; ced[2] = ep[2]; ced[3] = ep[3];
            #pragma unroll
            for (int nt = 0; nt < 4; ++nt)
                cbf[nt] = *(const bf16x8*)&hb[((size_t)s * 4 + nt) * 512];
        }

        // ---- weight build + MFMA (consumes aj loaded last iteration) ----
        const int* av = (const int*)aj;
        #pragma unroll
        for (int mt = 0; mt < 2; ++mt) {
            union { unsigned int u[4]; bf16x8 v; } af;
            #pragma unroll
            for (int p = 0; p < 4; ++p) {
                const float4 e = ced[p];     // {edz(2p), edw(2p), edz(2p+1), edw(2p+1)}
                floatx2 e0; e0[0] = e.x; e0[1] = e.y;
                floatx2 e1; e1[0] = e.z; e1[1] = e.w;
                const floatx2 pa = es12[mt] * e0;
                const floatx2 pb = es12[mt] * e1;
                float wa = fmaxf(pa[0], pa[1]);   // leaky-relu in exp domain
                float wb = fmaxf(pb[0], pb[1]);
                wa = (av[mt * 8 + 2 * p]     > 0) ? wa : 0.0f;
                wb = (av[mt * 8 + 2 * p + 1] > 0) ? wb : 0.0f;
                af.u[p] = __builtin_amdgcn_perm(__float_as_uint(wb), __float_as_uint(wa),
                                                0x07060302u);
            }
            #pragma unroll
            for (int nt = 0; nt < 4; ++nt)
                acc[mt][nt] = __builtin_amdgcn_mfma_f32_16x16x32_bf16(af.v, cbf[nt], acc[mt][nt], 0, 0, 0);
            accd[mt] = __builtin_amdgcn_mfma_f32_16x16x32_bf16(af.v, bones.v, accd[mt], 0, 0, 0);
        }

        // ---- reload adj for step s+1 into the same registers (depth-1, ~1 step cover) ----
        const int sn = (s + 1 < NSTEP) ? s + 1 : s;
        {
            const int4* p0 = (const int4*)(arow0 + (size_t)sn * 32);
            const int4* p1 = (const int4*)(arow1 + (size_t)sn * 32);
            aj[0] = p0[0]; aj[1] = p0[1]; aj[2] = p1[0]; aj[3] = p1[1];
        }
    }

    // ---- epilogue: disjoint per-split writes ----
    const size_t sOut = (size_t)blockIdx.y * n * HD;
    #pragma unroll
    for (int mt = 0; mt < 2; ++mt)
        #pragma unroll
        for (int nt = 0; nt < 4; ++nt)
            #pragma unroll
            for (int r = 0; r < 4; ++r)
                outsp[sOut + (size_t)(i0 + mt * 16 + q * 4 + r) * HD + wave * ODIM + nt * 16 + l16] = acc[mt][nt][r];
    if (l16 == 0) {
        #pragma unroll
        for (int mt = 0; mt < 2; ++mt)
            #pragma unroll
            for (int r = 0; r < 4; ++r)
                densp[((size_t)blockIdx.y * n + i0 + mt * 16 + q * 4 + r) * HEADS + wave] = accd[mt][r];
    }
}

// ============ normalize: out = sum_s outsp / sum_s densp ============
__global__ __launch_bounds__(256) void normalize(const float* __restrict__ outsp,
                                                 const float* __restrict__ densp,
                                                 float* __restrict__ out, int n, int splits) {
    const int g = blockIdx.x * 256 + threadIdx.x;
    const int i = g >> 6;
    const int c4 = (g & 63) * 4;
    const int head = c4 >> 6;
    float den = 0.f;
    for (int s = 0; s < splits; ++s) den += densp[((size_t)s * n + i) * HEADS + head];
    float4 v = {0.f, 0.f, 0.f, 0.f};
    for (int s = 0; s < splits; ++s) {
        const float4 t = *(const float4*)&outsp[(size_t)s * n * HD + (size_t)i * HD + c4];
        v.x += t.x; v.y += t.y; v.z += t.z; v.w += t.w;
    }
    const float inv = 1.0f / den;
    v.x *= inv; v.y *= inv; v.z *= inv; v.w *= inv;
    *(float4*)&out[(size_t)i * HD + c4] = v;
}

extern "C" void kernel_launch(void* const* d_in, const int* in_sizes, int n_in,
                              void* d_out, int out_size, void* d_ws, size_t ws_size,
                              hipStream_t stream) {
    const float* x   = (const float*)d_in[0];
    const int*   adj = (const int*)d_in[1];
    const float* W   = (const float*)d_in[2];
    const float* att = (const float*)d_in[3];
    float* out = (float*)d_out;

    const int in_dim = in_sizes[2] / HD;   // 256
    const int n = in_sizes[0] / in_dim;    // 4096

    char* ws = (char*)d_ws;
    size_t off = 0;
    auto alloc = [&](size_t bytes) -> void* {
        void* p = ws + off; off += (bytes + 255) & ~(size_t)255; return p;
    };
    __hip_bfloat16* xh = (__hip_bfloat16*)alloc((size_t)n * in_dim * 2);
    __hip_bfloat16* xl = (__hip_bfloat16*)alloc((size_t)n * in_dim * 2);
    __hip_bfloat16* wh = (__hip_bfloat16*)alloc((size_t)in_dim * HD * 2);
    __hip_bfloat16* wl = (__hip_bfloat16*)alloc((size_t)in_dim * HD * 2);
    float2* esrc = (float2*)alloc((size_t)HEADS * n * 8);
    float2* edst = (float2*)alloc((size_t)HEADS * n * 8);
    __hip_bfloat16* hbB = (__hip_bfloat16*)alloc((size_t)n * HD * 2);

    const size_t outB = (size_t)n * HD * 4, denB = (size_t)n * HEADS * 4;
    int splits = (ws_size >= off + 8 * (outB + denB)) ? 8 : 4;   // 8 -> 1024 blocks = 4/CU
    float* densp = (float*)alloc((size_t)splits * denB);
    float* outsp = (float*)alloc((size_t)splits * outB);

    const int nxb = (n / 16) * (in_dim / 32) * 64 / 256;
    const int nwb = (HD / 16) * (in_dim / 32) * 64 / 256;
    pack_xw<<<nxb + nwb, 256, 0, stream>>>(x, W, xh, xl, wh, wl, in_dim, nxb);
    gemm_fused<<<dim3(n / 32, HEADS), 128, 0, stream>>>(xh, xl, wh, wl, att, esrc, edst, hbB, n, in_dim);
    aggregate<<<dim3(n / 32, splits), 256, 0, stream>>>(adj, esrc, edst, hbB, outsp, densp, n, n / splits);
    normalize<<<n * 64 / 256, 256, 0, stream>>>(outsp, densp, out, n, splits);
}

// Round 8
// 143.994 us; speedup vs baseline: 1.1679x; 1.1679x over previous
//
#include <hip/hip_runtime.h>
#include <hip/hip_bf16.h>

#define HEADS 4
#define ODIM 64
#define HD 256          // HEADS*ODIM
#define NEG_SLOPE 0.2f
#define SPLITS 8        // KR = 4096/8 = 512 (edL LDS tile is sized for this)

typedef __attribute__((ext_vector_type(8))) short bf16x8;
typedef __attribute__((ext_vector_type(4))) float floatx4;
typedef __attribute__((ext_vector_type(2))) float floatx2;

// ============ pack x and W -> bf16 hi/lo MFMA fragments (one launch) ============
__global__ __launch_bounds__(256) void pack_xw(const float* __restrict__ x,
                                               const float* __restrict__ W,
                                               __hip_bfloat16* __restrict__ xh,
                                               __hip_bfloat16* __restrict__ xl,
                                               __hip_bfloat16* __restrict__ wh,
                                               __hip_bfloat16* __restrict__ wl,
                                               int K, int nxb) {
    const int b = blockIdx.x;
    const int Kc = K >> 5;
    if (b < nxb) {
        const int g = b * 256 + threadIdx.x;
        const int lane = g & 63, frag = g >> 6;
        const int kc = frag % Kc, mc = frag / Kc;
        const int l16 = lane & 15, q = lane >> 4;
        const float* src = x + (size_t)(mc * 16 + l16) * K + kc * 32 + q * 8;
        const float4 v0 = *(const float4*)src;
        const float4 v1 = *(const float4*)(src + 4);
        const float vv[8] = {v0.x, v0.y, v0.z, v0.w, v1.x, v1.y, v1.z, v1.w};
        union { __hip_bfloat16 b[8]; bf16x8 v; } H, L;
        #pragma unroll
        for (int p = 0; p < 8; ++p) {
            H.b[p] = __float2bfloat16(vv[p]);
            L.b[p] = __float2bfloat16(vv[p] - __bfloat162float(H.b[p]));
        }
        *(bf16x8*)&xh[(size_t)frag * 512 + lane * 8] = H.v;
        *(bf16x8*)&xl[(size_t)frag * 512 + lane * 8] = L.v;
    } else {
        const int g = (b - nxb) * 256 + threadIdx.x;
        const int lane = g & 63, frag = g >> 6;
        const int kc = frag % Kc, nc = frag / Kc;
        const int l16 = lane & 15, q = lane >> 4;
        union { __hip_bfloat16 b[8]; bf16x8 v; } H, L;
        #pragma unroll
        for (int p = 0; p < 8; ++p) {
            const float w = W[(size_t)(kc * 32 + q * 8 + p) * HD + nc * 16 + l16];
            H.b[p] = __float2bfloat16(w);
            L.b[p] = __float2bfloat16(w - __bfloat162float(H.b[p]));
        }
        *(bf16x8*)&wh[(size_t)frag * 512 + lane * 8] = H.v;
        *(bf16x8*)&wl[(size_t)frag * 512 + lane * 8] = L.v;
    }
}

// ============ fused GEMM: h = x@W (hi/lo bf16 MFMA) + exp epilogue + B-frag pack of h ============
__global__ __launch_bounds__(128) void gemm_fused(
    const __hip_bfloat16* __restrict__ xh, const __hip_bfloat16* __restrict__ xl,
    const __hip_bfloat16* __restrict__ wh, const __hip_bfloat16* __restrict__ wl,
    const float* __restrict__ att, float2* __restrict__ esrc, float2* __restrict__ edst,
    __hip_bfloat16* __restrict__ hbB, int n, int K) {

    __shared__ __hip_bfloat16 T[64][40];

    const int tid = threadIdx.x, wave = tid >> 6, lane = tid & 63;
    const int q = lane >> 4, l16 = lane & 15;
    const int m0 = blockIdx.x * 32;
    const int head = blockIdx.y;
    const int Kc = K >> 5;
    const int mc = (m0 >> 4) + wave;

    floatx4 acc[4] = {{0.f,0.f,0.f,0.f},{0.f,0.f,0.f,0.f},{0.f,0.f,0.f,0.f},{0.f,0.f,0.f,0.f}};

    const __hip_bfloat16* Axh = xh + (size_t)mc * Kc * 512 + lane * 8;
    const __hip_bfloat16* Axl = xl + (size_t)mc * Kc * 512 + lane * 8;
    const __hip_bfloat16* Bwh = wh + lane * 8;
    const __hip_bfloat16* Bwl = wl + lane * 8;
    #pragma unroll 2
    for (int kc = 0; kc < Kc; ++kc) {
        const bf16x8 ah = *(const bf16x8*)(Axh + (size_t)kc * 512);
        const bf16x8 al = *(const bf16x8*)(Axl + (size_t)kc * 512);
        bf16x8 bh[4], bl[4];
        #pragma unroll
        for (int nt = 0; nt < 4; ++nt) {
            const size_t fo = (size_t)((head * 4 + nt) * Kc + kc) * 512;
            bh[nt] = *(const bf16x8*)(Bwh + fo);
            bl[nt] = *(const bf16x8*)(Bwl + fo);
        }
        #pragma unroll
        for (int nt = 0; nt < 4; ++nt)
            acc[nt] = __builtin_amdgcn_mfma_f32_16x16x32_bf16(ah, bh[nt], acc[nt], 0, 0, 0);
        #pragma unroll
        for (int nt = 0; nt < 4; ++nt)
            acc[nt] = __builtin_amdgcn_mfma_f32_16x16x32_bf16(ah, bl[nt], acc[nt], 0, 0, 0);
        #pragma unroll
        for (int nt = 0; nt < 4; ++nt)
            acc[nt] = __builtin_amdgcn_mfma_f32_16x16x32_bf16(al, bh[nt], acc[nt], 0, 0, 0);
    }

    // ---- exp epilogue ----
    float as_v[4], ad_v[4];
    #pragma unroll
    for (int nt = 0; nt < 4; ++nt) {
        as_v[nt] = att[head * 2 * ODIM + nt * 16 + l16];
        ad_v[nt] = att[head * 2 * ODIM + ODIM + nt * 16 + l16];
    }
    #pragma unroll
    for (int r = 0; r < 4; ++r) {
        float ps = 0.f, pd = 0.f;
        #pragma unroll
        for (int nt = 0; nt < 4; ++nt) {
            ps = fmaf(acc[nt][r], as_v[nt], ps);
            pd = fmaf(acc[nt][r], ad_v[nt], pd);
        }
        #pragma unroll
        for (int m = 1; m <= 8; m <<= 1) {
            ps += __shfl_xor(ps, m, 64);
            pd += __shfl_xor(pd, m, 64);
        }
        if (l16 == 0) {
            const int i = m0 + wave * 16 + q * 4 + r;
            esrc[head * n + i] = make_float2(__expf(ps), __expf(NEG_SLOPE * ps));
            edst[head * n + i] = make_float2(__expf(pd), __expf(NEG_SLOPE * pd));
        }
    }

    // ---- write h tile transposed to LDS as bf16 ----
    #pragma unroll
    for (int nt = 0; nt < 4; ++nt) {
        union { __hip_bfloat16 b[4]; uint2 u; } pk;
        #pragma unroll
        for (int r = 0; r < 4; ++r) pk.b[r] = __float2bfloat16(acc[nt][r]);
        *(uint2*)&T[nt * 16 + l16][wave * 16 + q * 4] = pk.u;
    }
    __syncthreads();

    // ---- emit packed B-frags of h ----
    #pragma unroll
    for (int ffi = 0; ffi < 2; ++ffi) {
        const int f = wave + ffi * 2;   // nt
        const bf16x8 v = *(const bf16x8*)&T[f * 16 + l16][q * 8];
        const size_t frag = ((size_t)head * (n >> 5) + (m0 >> 5)) * 4 + f;
        *(bf16x8*)&hbB[frag * 512 + lane * 8] = v;
    }
}

// ============ aggregate v8: one-barrier LDS staging + copy-free hbB pipeline ============
// block: 4 waves (wave = head), i-tile 32, K split 8-way (KR=512). Prologue stages
// adj-bits (2.2 KB) and edst slice (16 KB) into LDS with ONE barrier; the 16-step
// main loop reads adj/ed from LDS (lgkm, short latency) and pipelines hbB global
// loads depth-2 with two register sets and no rotation copies.
__global__ __launch_bounds__(256, 3) void aggregate(
    const int* __restrict__ adj, const float2* __restrict__ esrc,
    const float2* __restrict__ edst, const __hip_bfloat16* __restrict__ hbB,
    float* __restrict__ outsp, float* __restrict__ densp, int n, int KR) {

    __shared__ unsigned char bitsL[32][68];   // [row][byte]; byte L covers j = L*8..L*8+7
    __shared__ float2 edL[HEADS][512];        // dst-side exps for the block's K-range

    const int tid = threadIdx.x;
    const int wave = tid >> 6, lane = tid & 63;
    const int q = lane >> 4, l16 = lane & 15;
    const int i0 = blockIdx.x * 32;
    const int K0 = blockIdx.y * KR;

    // ---- stage adj rectangle as bitmasks (coalesced: 2 KB contiguous per row) ----
    {
        const int r0 = i0 + wave * 8;
        #pragma unroll
        for (int rr = 0; rr < 8; ++rr) {
            const int4* ap = (const int4*)(adj + (size_t)(r0 + rr) * n + K0 + lane * 8);
            const int4 a = ap[0], b = ap[1];
            unsigned int by = (unsigned int)(a.x > 0)
                            | ((unsigned int)(a.y > 0) << 1)
                            | ((unsigned int)(a.z > 0) << 2)
                            | ((unsigned int)(a.w > 0) << 3)
                            | ((unsigned int)(b.x > 0) << 4)
                            | ((unsigned int)(b.y > 0) << 5)
                            | ((unsigned int)(b.z > 0) << 6)
                            | ((unsigned int)(b.w > 0) << 7);
            bitsL[wave * 8 + rr][lane] = (unsigned char)by;
        }
    }
    // ---- stage edst slice (coalesced float2 reads) ----
    for (int t = tid; t < HEADS * 512; t += 256) {
        const int h = t >> 9, j = t & 511;
        edL[h][j] = edst[(size_t)h * n + K0 + j];
    }

    // src-side exps for this lane's two rows (head = wave)
    floatx2 es12[2];
    #pragma unroll
    for (int mt = 0; mt < 2; ++mt) {
        const float2 e = esrc[wave * n + i0 + mt * 16 + l16];
        es12[mt][0] = e.x; es12[mt][1] = e.y;
    }

    // ones-column B-frag for MFMA-based denominator
    union { short s[8]; bf16x8 v; } bones;
    #pragma unroll
    for (int p = 0; p < 8; ++p) bones.s[p] = (l16 == 0) ? (short)0x3F80 : (short)0;

    floatx4 acc[2][4];
    floatx4 accd[2];
    #pragma unroll
    for (int mt = 0; mt < 2; ++mt) {
        accd[mt] = (floatx4){0.f, 0.f, 0.f, 0.f};
        #pragma unroll
        for (int nt = 0; nt < 4; ++nt) acc[mt][nt] = (floatx4){0.f, 0.f, 0.f, 0.f};
    }

    __syncthreads();   // the ONLY barrier

    const __hip_bfloat16* hb = hbB + ((size_t)wave * (n >> 5) + (K0 >> 5)) * 4 * 512 + lane * 8;
    const int NSTEP = KR >> 5;   // 16

    auto loadBF = [&](int s, bf16x8* dst) {
        #pragma unroll
        for (int nt = 0; nt < 4; ++nt)
            dst[nt] = *(const bf16x8*)&hb[((size_t)s * 4 + nt) * 512];
    };

    auto computeStep = [&](int s, const bf16x8* bfr) {
        // adjacency bytes for this lane's two rows (LDS dword, byte q)
        const unsigned int bm0 = (*(const unsigned int*)&bitsL[l16][s * 4] >> (q * 8)) & 0xFFu;
        const unsigned int bm1 = (*(const unsigned int*)&bitsL[16 + l16][s * 4] >> (q * 8)) & 0xFFu;
        // dst exps for this lane's 8 j's (LDS b128 x4, 16-lane broadcast)
        const float4* ep = (const float4*)&edL[wave][s * 32 + q * 8];
        const float4 e01 = ep[0], e23 = ep[1], e45 = ep[2], e67 = ep[3];
        floatx2 ed[8];
        ed[0][0]=e01.x; ed[0][1]=e01.y;  ed[1][0]=e01.z; ed[1][1]=e01.w;
        ed[2][0]=e23.x; ed[2][1]=e23.y;  ed[3][0]=e23.z; ed[3][1]=e23.w;
        ed[4][0]=e45.x; ed[4][1]=e45.y;  ed[5][0]=e45.z; ed[5][1]=e45.w;
        ed[6][0]=e67.x; ed[6][1]=e67.y;  ed[7][0]=e67.z; ed[7][1]=e67.w;
        #pragma unroll
        for (int mt = 0; mt < 2; ++mt) {
            const unsigned int bm = mt ? bm1 : bm0;
            union { unsigned int u[4]; bf16x8 v; } af;
            #pragma unroll
            for (int p = 0; p < 4; ++p) {
                const floatx2 pa = es12[mt] * ed[2 * p];
                const floatx2 pb = es12[mt] * ed[2 * p + 1];
                const float wa = fmaxf(pa[0], pa[1]);   // leaky-relu in exp domain
                const float wb = fmaxf(pb[0], pb[1]);
                const unsigned int mm = ((bm >> (2 * p)) & 1u) * 0xFFFFu
                                      | ((bm >> (2 * p + 1)) & 1u) * 0xFFFF0000u;
                af.u[p] = __builtin_amdgcn_perm(__float_as_uint(wb), __float_as_uint(wa),
                                                0x07060302u) & mm;
            }
            #pragma unroll
            for (int nt = 0; nt < 4; ++nt)
                acc[mt][nt] = __builtin_amdgcn_mfma_f32_16x16x32_bf16(af.v, bfr[nt], acc[mt][nt], 0, 0, 0);
            accd[mt] = __builtin_amdgcn_mfma_f32_16x16x32_bf16(af.v, bones.v, accd[mt], 0, 0, 0);
        }
    };

    // ---- copy-free depth-2 pipeline over two register sets ----
    bf16x8 bA[4], bB[4];
    loadBF(0, bA);
    loadBF(1, bB);
    for (int s = 0; s < NSTEP; s += 2) {
        computeStep(s, bA);
        if (s + 2 < NSTEP) loadBF(s + 2, bA);
        computeStep(s + 1, bB);
        if (s + 3 < NSTEP) loadBF(s + 3, bB);
    }

    // ---- epilogue: disjoint per-split writes ----
    const size_t sOut = (size_t)blockIdx.y * n * HD;
    #pragma unroll
    for (int mt = 0; mt < 2; ++mt)
        #pragma unroll
        for (int nt = 0; nt < 4; ++nt)
            #pragma unroll
            for (int r = 0; r < 4; ++r)
                outsp[sOut + (size_t)(i0 + mt * 16 + q * 4 + r) * HD + wave * ODIM + nt * 16 + l16] = acc[mt][nt][r];
    if (l16 == 0) {
        #pragma unroll
        for (int mt = 0; mt < 2; ++mt)
            #pragma unroll
            for (int r = 0; r < 4; ++r)
                densp[((size_t)blockIdx.y * n + i0 + mt * 16 + q * 4 + r) * HEADS + wave] = accd[mt][r];
    }
}

// ============ normalize: out = sum_s outsp / sum_s densp ============
__global__ __launch_bounds__(256) void normalize(const float* __restrict__ outsp,
                                                 const float* __restrict__ densp,
                                                 float* __restrict__ out, int n, int splits) {
    const int g = blockIdx.x * 256 + threadIdx.x;
    const int i = g >> 6;
    const int c4 = (g & 63) * 4;
    const int head = c4 >> 6;
    float den = 0.f;
    for (int s = 0; s < splits; ++s) den += densp[((size_t)s * n + i) * HEADS + head];
    float4 v = {0.f, 0.f, 0.f, 0.f};
    for (int s = 0; s < splits; ++s) {
        const float4 t = *(const float4*)&outsp[(size_t)s * n * HD + (size_t)i * HD + c4];
        v.x += t.x; v.y += t.y; v.z += t.z; v.w += t.w;
    }
    const float inv = 1.0f / den;
    v.x *= inv; v.y *= inv; v.z *= inv; v.w *= inv;
    *(float4*)&out[(size_t)i * HD + c4] = v;
}

extern "C" void kernel_launch(void* const* d_in, const int* in_sizes, int n_in,
                              void* d_out, int out_size, void* d_ws, size_t ws_size,
                              hipStream_t stream) {
    const float* x   = (const float*)d_in[0];
    const int*   adj = (const int*)d_in[1];
    const float* W   = (const float*)d_in[2];
    const float* att = (const float*)d_in[3];
    float* out = (float*)d_out;

    const int in_dim = in_sizes[2] / HD;   // 256
    const int n = in_sizes[0] / in_dim;    // 4096

    char* ws = (char*)d_ws;
    size_t off = 0;
    auto alloc = [&](size_t bytes) -> void* {
        void* p = ws + off; off += (bytes + 255) & ~(size_t)255; return p;
    };
    __hip_bfloat16* xh = (__hip_bfloat16*)alloc((size_t)n * in_dim * 2);
    __hip_bfloat16* xl = (__hip_bfloat16*)alloc((size_t)n * in_dim * 2);
    __hip_bfloat16* wh = (__hip_bfloat16*)alloc((size_t)in_dim * HD * 2);
    __hip_bfloat16* wl = (__hip_bfloat16*)alloc((size_t)in_dim * HD * 2);
    float2* esrc = (float2*)alloc((size_t)HEADS * n * 8);
    float2* edst = (float2*)alloc((size_t)HEADS * n * 8);
    __hip_bfloat16* hbB = (__hip_bfloat16*)alloc((size_t)n * HD * 2);

    const size_t outB = (size_t)n * HD * 4, denB = (size_t)n * HEADS * 4;
    float* densp = (float*)alloc((size_t)SPLITS * denB);
    float* outsp = (float*)alloc((size_t)SPLITS * outB);   // ~36.5 MB total ws — fits (ws >= 256 MB)

    const int nxb = (n / 16) * (in_dim / 32) * 64 / 256;
    const int nwb = (HD / 16) * (in_dim / 32) * 64 / 256;
    pack_xw<<<nxb + nwb, 256, 0, stream>>>(x, W, xh, xl, wh, wl, in_dim, nxb);
    gemm_fused<<<dim3(n / 32, HEADS), 128, 0, stream>>>(xh, xl, wh, wl, att, esrc, edst, hbB, n, in_dim);
    aggregate<<<dim3(n / 32, SPLITS), 256, 0, stream>>>(adj, esrc, edst, hbB, outsp, densp, n, n / SPLITS);
    normalize<<<n * 64 / 256, 256, 0, stream>>>(outsp, densp, out, n, SPLITS);
}